// Round 4
// baseline (961.305 us; speedup 1.0000x reference)
//
#include <hip/hip_runtime.h>

// HydraBackbonePlus: 10 dilations x {X, diffX} x 32 groups, 9-tap grouped dilated
// conv (8 out-ch per group), per-position argmax/argmin over the 8 channels,
// histogram-reduced to (32, 1280, 8) with relu.
//
// R4 changes vs R3:
//  - template<int DI> kernel per dilation (10 launches): every loop bound /
//    stride / divisor is constexpr. R1-R3's runtime-dynamic TM/CL/MC kept
//    extra values live and pushed the allocator into scratch spills
//    (WRITE_SIZE exactly 224 MB = 22 KB/block = ~22 regs x 256 thr spilled).
//    Constant bounds + unroll collapse addressing to immediates.
//  - exact per-di grids (keeps the d>=256 padded-compute elimination).

#define NDIL  10
#define NB    32     // batch
#define CIN   12
#define SEQ   8192
#define NG    32     // groups
#define CPER  6      // channels gathered per group
#define OUTCH 1280   // 10*2*2*32

template <int DI>
__global__ __launch_bounds__(256, 2) void hydra_di(
    const float* __restrict__ X, const float* __restrict__ W,
    const int* __restrict__ I, float* __restrict__ out) {

  constexpr int d     = 1 << DI;
  constexpr int R     = d < 8 ? d : 8;
  constexpr int rbits = DI < 3 ? DI : 3;
  constexpr int Mmax  = (SEQ + d - 1) / d;
  constexpr int TMf   = 512 / R;
  constexpr int TM    = TMf < Mmax ? TMf : Mmax;   // DI=8 -> 32, DI=9 -> 16
  constexpr int MC    = (Mmax + TM - 1) / TM;
  constexpr int RC    = d / R;
  constexpr int SR    = TM + 12;                   // row stride, mult of 4
  constexpr int CS    = R * SR + 4;                // channel stride
  constexpr int CL    = (R == 8) ? TM : (TM >> (3 - rbits));  // per-thread m-count
  constexpr int NBJ   = RC * MC;                   // blocks per (j,b)

  __shared__ float Xs[CIN * CS];

  // ---- decode blockIdx -> (j, b, rc, mcid), all-constant divisors ----
  int rem = blockIdx.x;
  int j = 0;
  if (rem >= NB * NBJ) { j = 1; rem -= NB * NBJ; }
  int b    = rem / NBJ;
  int r2   = rem % NBJ;
  int rc   = r2 / MC;
  int mcid = r2 % MC;

  const int L  = SEQ - j;
  const int r0 = rc * R;
  const int m0 = mcid * TM;
  const int tid = threadIdx.x;

  // ---- stage X (or diffX) tile into LDS, zero-padded ----
  for (int ch = 0; ch < CIN; ++ch) {
    const float* xb = X + ((size_t)b * CIN + ch) * SEQ;
    float* dst = Xs + ch * CS;
    for (int f = tid; f < R * SR; f += 256) {
      int rr = f & (R - 1);
      int mm = f >> rbits;
      int mp = m0 + mm - 4;
      int pos = r0 + rr + mp * d;
      float v = 0.f;
      if (mp >= 0 && mm < TM + 9 && pos < L)
        v = (j == 0) ? xb[pos] : (xb[pos + 1] - xb[pos]);
      dst[rr * SR + mm] = v;
    }
  }
  __syncthreads();

  // ---- per-thread setup: group, weights (72 regs), channel bases ----
  int g = tid >> 3, s = tid & 7;
  float Wr[8][9];
  {
    const float* wp = W + (size_t)((DI * 2 + j) * 256 + g * 8) * 9;
#pragma unroll
    for (int k = 0; k < 8; ++k)
#pragma unroll
      for (int t = 0; t < 9; ++t) Wr[k][t] = wp[k * 9 + t];
  }
  const float* base[CPER];
  {
    const int* ip = I + ((DI * 2 + j) * NG + g) * CPER;
#pragma unroll
    for (int i = 0; i < CPER; ++i) base[i] = Xs + ip[i] * CS;
  }

  float cmx[8] = {0.f, 0.f, 0.f, 0.f, 0.f, 0.f, 0.f, 0.f};
  float cmn[8] = {0.f, 0.f, 0.f, 0.f, 0.f, 0.f, 0.f, 0.f};

  // thread -> (row, m-subrange). R==8: row s, all TM. R<8: row = s&(R-1),
  // m-subrange of constexpr length CL.
  int rr, mst;
  if (R == 8) { rr = s;           mst = 0; }
  else        { rr = s & (R - 1); mst = (s >> rbits) * CL; }

  {
    int rowoff = rr * SR + mst;
    int pos = (r0 + rr) + (m0 + mst) * d;

    auto ldsum = [&](int idx) {
      float4 r = *reinterpret_cast<const float4*>(base[0] + idx);
#pragma unroll
      for (int i = 1; i < CPER; ++i) {
        float4 t = *reinterpret_cast<const float4*>(base[i] + idx);
        r.x += t.x; r.y += t.y; r.z += t.z; r.w += t.w;
      }
      return r;
    };

    float4 w0 = ldsum(rowoff + 0);
    float4 w1 = ldsum(rowoff + 4);
#pragma unroll 2
    for (int st = 0; st < CL; st += 4) {
      float4 w2 = ldsum(rowoff + st + 8);
      float win[12] = {w0.x, w0.y, w0.z, w0.w,
                       w1.x, w1.y, w1.z, w1.w,
                       w2.x, w2.y, w2.z, w2.w};
#pragma unroll
      for (int p = 0; p < 4; ++p) {
        float z[8];
#pragma unroll
        for (int k = 0; k < 8; ++k) {
          float acc = Wr[k][0] * win[p];
#pragma unroll
          for (int t = 1; t < 9; ++t) acc = fmaf(Wr[k][t], win[p + t], acc);
          z[k] = acc;
        }
        if (pos < L) {
          float mx = fmaxf(fmaxf(fmaxf(z[0], z[1]), fmaxf(z[2], z[3])),
                           fmaxf(fmaxf(z[4], z[5]), fmaxf(z[6], z[7])));
          float mn = fminf(fminf(fminf(z[0], z[1]), fminf(z[2], z[3])),
                           fminf(fminf(z[4], z[5]), fminf(z[6], z[7])));
#pragma unroll
          for (int k = 0; k < 8; ++k) {
            cmx[k] += (z[k] == mx) ? z[k] : 0.f;
            cmn[k] += (z[k] == mn) ? 1.f : 0.f;
          }
        }
        pos += d;
      }
      w0 = w1; w1 = w2;
    }
  }

  // ---- reduce across the 8 threads of each group (consecutive lanes) ----
#pragma unroll
  for (int k = 0; k < 8; ++k) {
#pragma unroll
    for (int off = 4; off > 0; off >>= 1) {
      cmx[k] += __shfl_down(cmx[k], off);
      cmn[k] += __shfl_down(cmn[k], off);
    }
  }
  if (s == 0) {
    int cbase = (DI * 2 + j) * 64;
    float* om = out + ((size_t)b * OUTCH + cbase + g) * 8;
    float* on = out + ((size_t)b * OUTCH + cbase + 32 + g) * 8;
#pragma unroll
    for (int k = 0; k < 8; ++k) {
      atomicAdd(om + k, cmx[k]);
      atomicAdd(on + k, cmn[k]);
    }
  }
}

__global__ void hydra_relu(float* __restrict__ out, int n) {
  int i = blockIdx.x * 256 + threadIdx.x;
  if (i < n) out[i] = fmaxf(out[i], 0.f);
}

static inline int grid_for(int di) {
  int d = 1 << di;
  int R = d < 8 ? d : 8;
  int Mmax = (SEQ + d - 1) / d;
  int TMf = 512 / R;
  int TM = TMf < Mmax ? TMf : Mmax;
  int MC = (Mmax + TM - 1) / TM;
  int RC = d / R;
  return 2 * NB * RC * MC;
}

extern "C" void kernel_launch(void* const* d_in, const int* in_sizes, int n_in,
                              void* d_out, int out_size, void* d_ws, size_t ws_size,
                              hipStream_t stream) {
  const float* X = (const float*)d_in[0];
  const float* W = (const float*)d_in[1];
  const int*   I = (const int*)d_in[2];
  float* out = (float*)d_out;

  // zero the accumulation target (harness poisons it with 0xAA)
  hipMemsetAsync(d_out, 0, (size_t)out_size * sizeof(float), stream);

  hydra_di<0><<<grid_for(0), 256, 0, stream>>>(X, W, I, out);
  hydra_di<1><<<grid_for(1), 256, 0, stream>>>(X, W, I, out);
  hydra_di<2><<<grid_for(2), 256, 0, stream>>>(X, W, I, out);
  hydra_di<3><<<grid_for(3), 256, 0, stream>>>(X, W, I, out);
  hydra_di<4><<<grid_for(4), 256, 0, stream>>>(X, W, I, out);
  hydra_di<5><<<grid_for(5), 256, 0, stream>>>(X, W, I, out);
  hydra_di<6><<<grid_for(6), 256, 0, stream>>>(X, W, I, out);
  hydra_di<7><<<grid_for(7), 256, 0, stream>>>(X, W, I, out);
  hydra_di<8><<<grid_for(8), 256, 0, stream>>>(X, W, I, out);
  hydra_di<9><<<grid_for(9), 256, 0, stream>>>(X, W, I, out);

  hydra_relu<<<(out_size + 255) / 256, 256, 0, stream>>>(out, out_size);
}

// Round 5
// 591.276 us; speedup vs baseline: 1.6258x; 1.6258x over previous
//
#include <hip/hip_runtime.h>

// HydraBackbonePlus: 10 dilations x {X, diffX} x 32 groups, 9-tap grouped dilated
// conv (8 out-ch per group), per-position argmax/argmin over 8 channels,
// histogram-reduced to (32, 1280, 8) with relu.
//
// R5: fused single launch (cross-di latency hiding, R0's win) + per-di
// constexpr bodies via switch (R4's no-spill win). Uniform 16 blocks/(j,b)
// for every di: R=min(d,16) residues, tile = 512 positions, d=512 does 2
// residue-chunks per block. LDS 30.9 KB -> 5 blocks/CU. Butterfly reduce +
// 2 wave-wide atomics (was 16 serialized per lane-0; contention 64->16-way).

#define NB    32
#define CIN   12
#define SEQ   8192
#define NG    32
#define CPER  6
#define OUTCH 1280
#define XS_FLOATS 7728   // 12 * 644 = max over DI of CIN*CS
#define GRID  10240      // 20 (di,j) * 32 b * 16 chunks

template <int DI>
__device__ __forceinline__ void hydra_body(
    const float* __restrict__ X, const float* __restrict__ W,
    const int* __restrict__ I, float* __restrict__ out,
    float* Xs, int j, int b, int chunk) {

  constexpr int d   = 1 << DI;
  constexpr int R   = (d < 16) ? d : 16;       // residues per tile row-set
  constexpr int rb  = (DI < 4) ? DI : 4;       // log2(R)
  constexpr int Mm  = SEQ / d;                 // m-extent of a residue
  constexpr int TMc = 512 / R;
  constexpr int TM  = (TMc < Mm) ? TMc : Mm;   // m per tile (DI=9 -> 16)
  constexpr int MC  = Mm / TM;
  constexpr int RC  = d / R;
  constexpr int NR  = (RC * MC) / 16;          // chunks per block: 1 (DI<9), 2 (DI=9)
  constexpr int SR  = TM + 8;                  // row stride (exact halo)
  constexpr int CS  = R * SR + 4;              // channel stride
  constexpr int CL  = (R >= 8) ? TM : (TM * R / 8);  // m per thread per rep
  constexpr int REP = (R == 16) ? 2 : 1;

  const int L = SEQ - j;
  const int tid = threadIdx.x;
  const int g = tid >> 3, s = tid & 7;

  // weights: 72 per thread (8 out-ch x 9 taps)
  float Wr[8][9];
  {
    const float* wp = W + (size_t)((DI * 2 + j) * 256 + g * 8) * 9;
#pragma unroll
    for (int k = 0; k < 8; ++k)
#pragma unroll
      for (int t = 0; t < 9; ++t) Wr[k][t] = wp[k * 9 + t];
  }
  const float* base[CPER];
  {
    const int* ip = I + ((DI * 2 + j) * NG + g) * CPER;
#pragma unroll
    for (int i = 0; i < CPER; ++i) base[i] = Xs + ip[i] * CS;
  }

  float cmx[8] = {0,0,0,0,0,0,0,0};
  float cmn[8] = {0,0,0,0,0,0,0,0};

  for (int n = 0; n < NR; ++n) {
    const int cidx = chunk + 16 * n;
    const int rc = cidx & (RC - 1);
    const int mc = cidx / RC;
    const int r0 = rc * R;
    const int m0 = mc * TM;

    if (NR > 1 && n) __syncthreads();

    // ---- stage 12-channel tile into LDS, zero-padded; guards hoisted ----
    {
      const float* xb0 = X + (size_t)b * CIN * SEQ;
      if (j == 0) {
        for (int f = tid; f < R * SR; f += 256) {
          int rr = f & (R - 1), mm = f >> rb, mp = m0 + mm - 4;
          int pos = r0 + rr + mp * d;
          bool ok = (mp >= 0) && (pos < L);
          int lo = rr * SR + mm;
          const float* xp = xb0 + pos;
#pragma unroll
          for (int ch = 0; ch < CIN; ++ch) {
            Xs[ch * CS + lo] = ok ? xp[0] : 0.f;
            xp += SEQ;
          }
        }
      } else {
        for (int f = tid; f < R * SR; f += 256) {
          int rr = f & (R - 1), mm = f >> rb, mp = m0 + mm - 4;
          int pos = r0 + rr + mp * d;
          bool ok = (mp >= 0) && (pos < L);
          int lo = rr * SR + mm;
          const float* xp = xb0 + pos;
#pragma unroll
          for (int ch = 0; ch < CIN; ++ch) {
            Xs[ch * CS + lo] = ok ? (xp[1] - xp[0]) : 0.f;
            xp += SEQ;
          }
        }
      }
    }
    __syncthreads();

    // ---- compute: sliding 12-float window, 8-ch conv, argmax/min histogram ----
#pragma unroll
    for (int rep = 0; rep < REP; ++rep) {
      int rr = (R == 16) ? (s + (rep << 3)) : (s & (R - 1));
      int mst = (R >= 8) ? 0 : ((s >> rb) * CL);
      int rowoff = rr * SR + mst;
      int pos = (r0 + rr) + (m0 + mst) * d;

      auto ldsum = [&](int idx) {
        float4 r = *reinterpret_cast<const float4*>(base[0] + idx);
#pragma unroll
        for (int i = 1; i < CPER; ++i) {
          float4 t = *reinterpret_cast<const float4*>(base[i] + idx);
          r.x += t.x; r.y += t.y; r.z += t.z; r.w += t.w;
        }
        return r;
      };

      float4 w0 = ldsum(rowoff);
      float4 w1 = ldsum(rowoff + 4);
#pragma unroll 2
      for (int st = 0; st < CL; st += 4) {
        float4 w2 = ldsum(rowoff + st + 8);
        float win[12] = {w0.x, w0.y, w0.z, w0.w,
                         w1.x, w1.y, w1.z, w1.w,
                         w2.x, w2.y, w2.z, w2.w};
#pragma unroll
        for (int p = 0; p < 4; ++p) {
          float z[8];
#pragma unroll
          for (int k = 0; k < 8; ++k) {
            float acc = Wr[k][0] * win[p];
#pragma unroll
            for (int t = 1; t < 9; ++t) acc = fmaf(Wr[k][t], win[p + t], acc);
            z[k] = acc;
          }
          if (pos < L) {
            float mx = fmaxf(fmaxf(fmaxf(z[0], z[1]), fmaxf(z[2], z[3])),
                             fmaxf(fmaxf(z[4], z[5]), fmaxf(z[6], z[7])));
            float mn = fminf(fminf(fminf(z[0], z[1]), fminf(z[2], z[3])),
                             fminf(fminf(z[4], z[5]), fminf(z[6], z[7])));
#pragma unroll
            for (int k = 0; k < 8; ++k) {
              cmx[k] += (z[k] == mx) ? z[k] : 0.f;
              cmn[k] += (z[k] == mn) ? 1.f : 0.f;
            }
          }
          pos += d;
        }
        w0 = w1; w1 = w2;
      }
    }
  }

  // ---- butterfly reduce over the 8 s-lanes; all lanes end with full sums ----
#pragma unroll
  for (int k = 0; k < 8; ++k) {
#pragma unroll
    for (int off = 1; off < 8; off <<= 1) {
      cmx[k] += __shfl_xor(cmx[k], off);
      cmn[k] += __shfl_xor(cmn[k], off);
    }
  }
  // lane s commits bin k=s: 2 wave-wide atomics instead of 16 serialized
  float vx = cmx[0], vn = cmn[0];
#pragma unroll
  for (int k = 1; k < 8; ++k) {
    vx = (s == k) ? cmx[k] : vx;
    vn = (s == k) ? cmn[k] : vn;
  }
  int cbase = (DI * 2 + j) * 64;
  float* om = out + ((size_t)b * OUTCH + cbase + g) * 8;
  atomicAdd(om + s, vx);          // cmax channel block
  atomicAdd(om + 256 + s, vn);    // cmin block: +32 channels * 8
}

__global__ __launch_bounds__(256, 2) void hydra_fused(
    const float* __restrict__ X, const float* __restrict__ W,
    const int* __restrict__ I, float* __restrict__ out) {
  __shared__ float Xs[XS_FLOATS];
  int u = blockIdx.x;
  int dj = u % 20;            // consecutive blocks interleave (di,j)
  int rest = u / 20;
  int b = rest & 31;
  int chunk = rest >> 5;
  int j = dj & 1;
  switch (dj >> 1) {
    case 0: hydra_body<0>(X, W, I, out, Xs, j, b, chunk); break;
    case 1: hydra_body<1>(X, W, I, out, Xs, j, b, chunk); break;
    case 2: hydra_body<2>(X, W, I, out, Xs, j, b, chunk); break;
    case 3: hydra_body<3>(X, W, I, out, Xs, j, b, chunk); break;
    case 4: hydra_body<4>(X, W, I, out, Xs, j, b, chunk); break;
    case 5: hydra_body<5>(X, W, I, out, Xs, j, b, chunk); break;
    case 6: hydra_body<6>(X, W, I, out, Xs, j, b, chunk); break;
    case 7: hydra_body<7>(X, W, I, out, Xs, j, b, chunk); break;
    case 8: hydra_body<8>(X, W, I, out, Xs, j, b, chunk); break;
    case 9: hydra_body<9>(X, W, I, out, Xs, j, b, chunk); break;
  }
}

__global__ void hydra_relu(float* __restrict__ out, int n) {
  int i = blockIdx.x * 256 + threadIdx.x;
  if (i < n) out[i] = fmaxf(out[i], 0.f);
}

extern "C" void kernel_launch(void* const* d_in, const int* in_sizes, int n_in,
                              void* d_out, int out_size, void* d_ws, size_t ws_size,
                              hipStream_t stream) {
  const float* X = (const float*)d_in[0];
  const float* W = (const float*)d_in[1];
  const int*   I = (const int*)d_in[2];
  float* out = (float*)d_out;

  hipMemsetAsync(d_out, 0, (size_t)out_size * sizeof(float), stream);
  hydra_fused<<<GRID, 256, 0, stream>>>(X, W, I, out);
  hydra_relu<<<(out_size + 255) / 256, 256, 0, stream>>>(out, out_size);
}

// Round 7
// 487.150 us; speedup vs baseline: 1.9733x; 1.2137x over previous
//
#include <hip/hip_runtime.h>

// HydraBackbonePlus: 10 dilations x {X, diffX} x 32 groups, 9-tap grouped dilated
// conv (8 out-ch per group), per-position argmax/argmin over 8 channels,
// histogram-reduced to (32, 1280, 8) with relu.
//
// R7 = R6 with the type fix: __builtin_amdgcn_cvt_pkrtz returns
// __fp16 ext_vector_type(2); h2_t now matches. R6 rationale:
//  - conv via v_dot2_f32_f16: weights packed half2 (40 regs, was 72 f32),
//    window packed via v_cvt_pkrtz. ~50 VALU slots per 4-pos conv vs ~300.
//  - cmn accumulated as int (v_cmp + v_addc idiom).
//  - __launch_bounds__(256,4): shrunken live set fits the 128 cap -> 4 waves/SIMD.

typedef __fp16 h2_t __attribute__((ext_vector_type(2)));

#define NB    32
#define CIN   12
#define SEQ   8192
#define NG    32
#define CPER  6
#define OUTCH 1280
#define XS_FLOATS 7728   // 12 * 644 = max over DI of CIN*CS
#define GRID  10240      // 20 (di,j) * 32 b * 16 chunks

template <int DI>
__device__ __forceinline__ void hydra_body(
    const float* __restrict__ X, const float* __restrict__ W,
    const int* __restrict__ I, float* __restrict__ out,
    float* Xs, int j, int b, int chunk) {

  constexpr int d   = 1 << DI;
  constexpr int R   = (d < 16) ? d : 16;       // residues per tile row-set
  constexpr int rb  = (DI < 4) ? DI : 4;       // log2(R)
  constexpr int Mm  = SEQ / d;                 // m-extent of a residue
  constexpr int TMc = 512 / R;
  constexpr int TM  = (TMc < Mm) ? TMc : Mm;   // m per tile (DI=9 -> 16)
  constexpr int MC  = Mm / TM;
  constexpr int RC  = d / R;
  constexpr int NR  = (RC * MC) / 16;          // chunks per block: 1 (DI<9), 2 (DI=9)
  constexpr int SR  = TM + 8;                  // row stride (exact halo)
  constexpr int CS  = R * SR + 4;              // channel stride
  constexpr int CL  = (R >= 8) ? TM : (TM * R / 8);  // m per thread per rep
  constexpr int REP = (R == 16) ? 2 : 1;

  const int L = SEQ - j;
  const int tid = threadIdx.x;
  const int g = tid >> 3, s = tid & 7;

  // weights: 8 out-ch x 9 taps -> 4 half2 + 1 f32 tail per channel (40 regs)
  h2_t Wp[8][4];
  float Wt[8];
  {
    const float* wp = W + (size_t)((DI * 2 + j) * 256 + g * 8) * 9;
#pragma unroll
    for (int k = 0; k < 8; ++k) {
#pragma unroll
      for (int t = 0; t < 4; ++t)
        Wp[k][t] = __builtin_amdgcn_cvt_pkrtz(wp[k * 9 + 2 * t], wp[k * 9 + 2 * t + 1]);
      Wt[k] = wp[k * 9 + 8];
    }
  }
  const float* base[CPER];
  {
    const int* ip = I + ((DI * 2 + j) * NG + g) * CPER;
#pragma unroll
    for (int i = 0; i < CPER; ++i) base[i] = Xs + ip[i] * CS;
  }

  float cmx[8] = {0,0,0,0,0,0,0,0};
  int   cmni[8] = {0,0,0,0,0,0,0,0};

  for (int n = 0; n < NR; ++n) {
    const int cidx = chunk + 16 * n;
    const int rc = cidx & (RC - 1);
    const int mc = cidx / RC;
    const int r0 = rc * R;
    const int m0 = mc * TM;

    if (NR > 1 && n) __syncthreads();

    // ---- stage 12-channel tile into LDS, zero-padded; guards hoisted ----
    {
      const float* xb0 = X + (size_t)b * CIN * SEQ;
      if (j == 0) {
        for (int f = tid; f < R * SR; f += 256) {
          int rr = f & (R - 1), mm = f >> rb, mp = m0 + mm - 4;
          int pos = r0 + rr + mp * d;
          bool ok = (mp >= 0) && (pos < L);
          int lo = rr * SR + mm;
          const float* xp = xb0 + pos;
#pragma unroll
          for (int ch = 0; ch < CIN; ++ch) {
            Xs[ch * CS + lo] = ok ? xp[0] : 0.f;
            xp += SEQ;
          }
        }
      } else {
        for (int f = tid; f < R * SR; f += 256) {
          int rr = f & (R - 1), mm = f >> rb, mp = m0 + mm - 4;
          int pos = r0 + rr + mp * d;
          bool ok = (mp >= 0) && (pos < L);
          int lo = rr * SR + mm;
          const float* xp = xb0 + pos;
#pragma unroll
          for (int ch = 0; ch < CIN; ++ch) {
            Xs[ch * CS + lo] = ok ? (xp[1] - xp[0]) : 0.f;
            xp += SEQ;
          }
        }
      }
    }
    __syncthreads();

    // ---- compute: sliding window, dot2 conv, argmax/min histogram ----
#pragma unroll
    for (int rep = 0; rep < REP; ++rep) {
      int rr = (R == 16) ? (s + (rep << 3)) : (s & (R - 1));
      int mst = (R >= 8) ? 0 : ((s >> rb) * CL);
      int rowoff = rr * SR + mst;
      int pos = (r0 + rr) + (m0 + mst) * d;

      auto ldsum = [&](int idx) {
        float4 r = *reinterpret_cast<const float4*>(base[0] + idx);
#pragma unroll
        for (int i = 1; i < CPER; ++i) {
          float4 t = *reinterpret_cast<const float4*>(base[i] + idx);
          r.x += t.x; r.y += t.y; r.z += t.z; r.w += t.w;
        }
        return r;
      };

      float4 w0 = ldsum(rowoff);
      float4 w1 = ldsum(rowoff + 4);
#pragma unroll 2
      for (int st = 0; st < CL; st += 4) {
        float4 w2 = ldsum(rowoff + st + 8);
        float xv[12] = {w0.x, w0.y, w0.z, w0.w,
                        w1.x, w1.y, w1.z, w1.w,
                        w2.x, w2.y, w2.z, w2.w};
        // even- and odd-aligned f16 pair windows covering xv[0..11]
        h2_t E[5], O[5];
#pragma unroll
        for (int i = 0; i < 5; ++i) {
          E[i] = __builtin_amdgcn_cvt_pkrtz(xv[2 * i],     xv[2 * i + 1]);
          O[i] = __builtin_amdgcn_cvt_pkrtz(xv[2 * i + 1], xv[2 * i + 2]);
        }
#pragma unroll
        for (int p = 0; p < 4; ++p) {
          float z[8];
          const h2_t* P = (p & 1) ? (O + (p >> 1)) : (E + (p >> 1));
          float tail = xv[8 + p];
#pragma unroll
          for (int k = 0; k < 8; ++k) {
            float acc = Wt[k] * tail;
            acc = __builtin_amdgcn_fdot2(Wp[k][3], P[3], acc, false);
            acc = __builtin_amdgcn_fdot2(Wp[k][2], P[2], acc, false);
            acc = __builtin_amdgcn_fdot2(Wp[k][1], P[1], acc, false);
            acc = __builtin_amdgcn_fdot2(Wp[k][0], P[0], acc, false);
            z[k] = acc;
          }
          if (pos < L) {
            float mx = fmaxf(fmaxf(fmaxf(z[0], z[1]), fmaxf(z[2], z[3])),
                             fmaxf(fmaxf(z[4], z[5]), fmaxf(z[6], z[7])));
            float mn = fminf(fminf(fminf(z[0], z[1]), fminf(z[2], z[3])),
                             fminf(fminf(z[4], z[5]), fminf(z[6], z[7])));
#pragma unroll
            for (int k = 0; k < 8; ++k) {
              cmx[k] += (z[k] == mx) ? z[k] : 0.f;
              cmni[k] += (z[k] == mn);   // v_cmp + v_addc
            }
          }
          pos += d;
        }
        w0 = w1; w1 = w2;
      }
    }
  }

  // ---- butterfly reduce over the 8 s-lanes; all lanes end with full sums ----
#pragma unroll
  for (int k = 0; k < 8; ++k) {
#pragma unroll
    for (int off = 1; off < 8; off <<= 1) {
      cmx[k]  += __shfl_xor(cmx[k], off);
      cmni[k] += __shfl_xor(cmni[k], off);
    }
  }
  // lane s commits bin k=s: 2 wave-wide atomics
  float vx = cmx[0];
  int   vn = cmni[0];
#pragma unroll
  for (int k = 1; k < 8; ++k) {
    vx = (s == k) ? cmx[k]  : vx;
    vn = (s == k) ? cmni[k] : vn;
  }
  int cbase = (DI * 2 + j) * 64;
  float* om = out + ((size_t)b * OUTCH + cbase + g) * 8;
  atomicAdd(om + s, vx);                  // cmax block
  atomicAdd(om + 256 + s, (float)vn);     // cmin block (+32 channels * 8)
}

__global__ __launch_bounds__(256, 4) void hydra_fused(
    const float* __restrict__ X, const float* __restrict__ W,
    const int* __restrict__ I, float* __restrict__ out) {
  __shared__ float Xs[XS_FLOATS];
  int u = blockIdx.x;
  int dj = u % 20;            // consecutive blocks interleave (di,j)
  int rest = u / 20;
  int b = rest & 31;
  int chunk = rest >> 5;
  int j = dj & 1;
  switch (dj >> 1) {
    case 0: hydra_body<0>(X, W, I, out, Xs, j, b, chunk); break;
    case 1: hydra_body<1>(X, W, I, out, Xs, j, b, chunk); break;
    case 2: hydra_body<2>(X, W, I, out, Xs, j, b, chunk); break;
    case 3: hydra_body<3>(X, W, I, out, Xs, j, b, chunk); break;
    case 4: hydra_body<4>(X, W, I, out, Xs, j, b, chunk); break;
    case 5: hydra_body<5>(X, W, I, out, Xs, j, b, chunk); break;
    case 6: hydra_body<6>(X, W, I, out, Xs, j, b, chunk); break;
    case 7: hydra_body<7>(X, W, I, out, Xs, j, b, chunk); break;
    case 8: hydra_body<8>(X, W, I, out, Xs, j, b, chunk); break;
    case 9: hydra_body<9>(X, W, I, out, Xs, j, b, chunk); break;
  }
}

__global__ void hydra_relu(float* __restrict__ out, int n) {
  int i = blockIdx.x * 256 + threadIdx.x;
  if (i < n) out[i] = fmaxf(out[i], 0.f);
}

extern "C" void kernel_launch(void* const* d_in, const int* in_sizes, int n_in,
                              void* d_out, int out_size, void* d_ws, size_t ws_size,
                              hipStream_t stream) {
  const float* X = (const float*)d_in[0];
  const float* W = (const float*)d_in[1];
  const int*   I = (const int*)d_in[2];
  float* out = (float*)d_out;

  (void)hipMemsetAsync(d_out, 0, (size_t)out_size * sizeof(float), stream);
  hydra_fused<<<GRID, 256, 0, stream>>>(X, W, I, out);
  hydra_relu<<<(out_size + 255) / 256, 256, 0, stream>>>(out, out_size);
}